// Round 2
// baseline (145.214 us; speedup 1.0000x reference)
//
#include <hip/hip_runtime.h>
#include <stdint.h>

// Problem constants: B=8, N=1024, I=256, O=256, R=8
// out[b,dst,o] = (sum_{src,r} adj[b,src,dst,r] * f[b,src,r,o]) / clip(sum_{src,r} adj, 1e-16)
// f = x @ weight  (per relation)
//
// Strategy:
//  prep_x : x fp32 -> bf16 copy (x_bf [8192][256])
//  prep_w : weight[r][i][o] -> W_t[o*8+r][256 i] bf16  (K-major rows for MFMA B frags)
//  k1     : f_t[b][o][k=src*8+r] = x @ W   (bf16 MFMA, 128x128 tiles, direct-global frags)
//  k2     : out-partials = adj^T @ f_t per batch, MT=32 dst x NT=256 o, KT=64 (8 src x 8 r),
//           split-K=2 (512 blocks), fused fp32 denom accumulation.
//           A (adj) reg-staged fp32->bf16 into swizzled LDS; B (f_t) via global_load_lds
//           with pre-swizzled source; frag reads = swizzled ds_read_b128.
//  k3     : sum split-K partials, divide by clamped denom.
//
// R1 fix: k2's k-loop trip count was half the src range (KT 32/64 -> 64/128).
// 1024 src / 8 src-per-kt = 128 kt total, 64 per split-K half.

typedef float          floatx4  __attribute__((ext_vector_type(4)));
typedef short          shortx8  __attribute__((ext_vector_type(8)));
typedef unsigned short ushortx4 __attribute__((ext_vector_type(4)));
typedef unsigned short ushortx8 __attribute__((ext_vector_type(8)));

__device__ __forceinline__ unsigned short f2bf(float f) {
  union { float f; unsigned int u; } v; v.f = f;
  unsigned int u = v.u + 0x7FFFu + ((v.u >> 16) & 1u);  // RNE
  return (unsigned short)(u >> 16);
}

__device__ __forceinline__ void gload16(const void* g, void* l) {
  __builtin_amdgcn_global_load_lds((__attribute__((address_space(1))) void*)g,
                                   (__attribute__((address_space(3))) void*)l,
                                   16, 0, 0);
}

// ---------------- prep kernels ----------------
__global__ __launch_bounds__(256) void prep_x(const float* __restrict__ x,
                                              unsigned short* __restrict__ xbf) {
  int t = blockIdx.x * 256 + threadIdx.x;          // 262144 threads, 8 elems each
  const float4* p = (const float4*)x + (size_t)t * 2;
  float4 a = p[0], b4 = p[1];
  ushortx8 o;
  o[0] = f2bf(a.x);  o[1] = f2bf(a.y);  o[2] = f2bf(a.z);  o[3] = f2bf(a.w);
  o[4] = f2bf(b4.x); o[5] = f2bf(b4.y); o[6] = f2bf(b4.z); o[7] = f2bf(b4.w);
  *(ushortx8*)(xbf + (size_t)t * 8) = o;
}

__global__ __launch_bounds__(256) void prep_w(const float* __restrict__ w,
                                              unsigned short* __restrict__ wt) {
  int id = blockIdx.x * 256 + threadIdx.x;         // 524288 = 8*256*256
  int r = id >> 16, i = (id >> 8) & 255, o = id & 255;
  float v = w[((size_t)(r * 256 + i) << 8) + o];   // weight[r][i][o], coalesced in o
  wt[((size_t)(o * 8 + r) << 8) + i] = f2bf(v);    // W_t[n'=o*8+r][i]
}

// ---------------- kernel 1: f_t = x @ W ----------------
// M=8192 (b,src), K=256 (i), N'=2048 (n'=o*8+r). Tile 128x128, 4 waves (2x2), 4x4 frags.
// Writes f_t[b][o][src*8+r] bf16 directly (block covers 16 o x 8 r x 128 src -> full lines).
__global__ __launch_bounds__(256) void k1_gemm(const unsigned short* __restrict__ xbf,
                                               const unsigned short* __restrict__ wt,
                                               unsigned short* __restrict__ ft) {
  int bid = blockIdx.x;                            // 64 m-tiles x 16 n-tiles
  int m0 = (bid >> 4) * 128, n0 = (bid & 15) * 128;
  int l = threadIdx.x & 63, w = threadIdx.x >> 6;
  int lr = l & 15, lg = l >> 4;
  int mw = m0 + (w >> 1) * 64, nw = n0 + (w & 1) * 64;

  floatx4 acc[4][4] = {};
#pragma unroll
  for (int ks = 0; ks < 8; ++ks) {                 // K = 256 = 8 * 32
    shortx8 a[4], b[4];
#pragma unroll
    for (int mi = 0; mi < 4; ++mi)
      a[mi] = *(const shortx8*)(xbf + (size_t)(mw + mi * 16 + lr) * 256 + ks * 32 + lg * 8);
#pragma unroll
    for (int ni = 0; ni < 4; ++ni)
      b[ni] = *(const shortx8*)(wt + (size_t)(nw + ni * 16 + lr) * 256 + ks * 32 + lg * 8);
#pragma unroll
    for (int mi = 0; mi < 4; ++mi)
#pragma unroll
      for (int ni = 0; ni < 4; ++ni)
        acc[mi][ni] = __builtin_amdgcn_mfma_f32_16x16x32_bf16(a[mi], b[ni], acc[mi][ni], 0, 0, 0);
  }
  // epilogue: C layout col=lane&15, row=(lane>>4)*4+reg
#pragma unroll
  for (int mi = 0; mi < 4; ++mi) {
#pragma unroll
    for (int ni = 0; ni < 4; ++ni) {
      int np = nw + ni * 16 + lr;
      int o = np >> 3, r = np & 7;
#pragma unroll
      for (int reg = 0; reg < 4; ++reg) {
        int row = mw + mi * 16 + lg * 4 + reg;     // global (b,src)
        int b8 = row >> 10, src = row & 1023;
        ft[((size_t)(b8 * 256 + o) << 13) + src * 8 + r] = f2bf(acc[mi][ni][reg]);
      }
    }
  }
}

// ---------------- kernel 2: out = adj^T @ f_t (+ denom) ----------------
// Per block: batch b, 32 dst rows, all 256 o cols, K-half (split-K=2).
// K = src*8+r (8192), KT=64 (8 src x 8 r per tile). 4 waves along o (64 each).
template <int KSPLIT>
__global__ __launch_bounds__(256) void k2_gemm(const float* __restrict__ adj,
                                               const unsigned short* __restrict__ ft,
                                               float* __restrict__ outp,
                                               float* __restrict__ pout,
                                               float* __restrict__ dpart) {
  __shared__ __align__(16) unsigned short Alds[32 * 64];   // [dst][64k], swizzled, 4KB
  __shared__ __align__(16) unsigned short Blds[256 * 64];  // [o][64k], swizzled, 32KB
  __shared__ float dsums[256];
  __shared__ float denr[32];

  int bid = blockIdx.x;
  int kc = (KSPLIT == 2) ? (bid >> 8) : 0;
  int inner = bid & 255;
  int b = inner & 7;                 // b = blk%8 -> batch pinned to one XCD (L2 locality for f_t[b])
  int dst0 = (inner >> 3) * 32;

  int t = threadIdx.x, l = t & 63, w = t >> 6;
  int lr = l & 15, lg = l >> 4;

  // A-staging assignment (fixed per thread): dst_l, r-half, base src lane
  int dst_l = (t & 63) >> 1;
  int rh = (t & 1) * 4;
  int srcA = t >> 6;                 // 0..3 (then +4 for second chunk)

  int orow_off = w * 8 + (l >> 3);   // B staging: o row offset per issue
  int csw = (l & 7) ^ (l >> 3);      // pre-swizzled source chunk (orow&7 == l>>3)

  const int KT = (KSPLIT == 2) ? 64 : 128;  // 8 src per kt; 1024 src total
  int src_base = kc * 512;
  const size_t adj_b = (size_t)b << 23;                 // b * 1024*1024*8
  const unsigned short* ftb = ft + ((size_t)b << 21);   // b * 256*8192

  float dsum = 0.f;
  floatx4 acc[2][4] = {};

  for (int kt = 0; kt < KT; ++kt) {
    int src0 = src_base + kt * 8;
    __syncthreads();                 // LDS reuse guard (also drains prior reads)
    // ---- stage A: adj fp32 -> bf16, swizzled; accumulate exact fp32 denom ----
#pragma unroll
    for (int j = 0; j < 2; ++j) {
      int src_l = srcA + j * 4;
      const float* ap = adj + adj_b + (((size_t)(src0 + src_l) << 10) + dst0 + dst_l) * 8 + rh;
      float4 v = *(const float4*)ap;
      dsum += v.x + v.y + v.z + v.w;
      ushortx4 h;
      h[0] = f2bf(v.x); h[1] = f2bf(v.y); h[2] = f2bf(v.z); h[3] = f2bf(v.w);
      int slot = src_l ^ (dst_l & 7);
      *(ushortx4*)&Alds[dst_l * 64 + slot * 8 + rh] = h;
    }
    // ---- stage B: f_t rows, direct global->LDS, pre-swizzled source ----
    int kbase = src0 * 8;
#pragma unroll
    for (int i = 0; i < 8; ++i) {
      int orow = i * 32 + orow_off;
      const unsigned short* g = ftb + ((size_t)orow << 13) + kbase + (csw << 3);
      gload16(g, &Blds[(i * 32 + w * 8) * 64]);   // wave-uniform LDS base
    }
    __syncthreads();
    // ---- compute: 2 k-substeps x (2 A-frags, 4 B-frags, 8 mfma) ----
#pragma unroll
    for (int s = 0; s < 2; ++s) {
      int slotbase = s * 4 + lg;
      shortx8 af[2], bfr[4];
#pragma unroll
      for (int mi = 0; mi < 2; ++mi) {
        int row = mi * 16 + lr;
        af[mi] = *(const shortx8*)&Alds[row * 64 + ((slotbase ^ (row & 7)) << 3)];
      }
#pragma unroll
      for (int ni = 0; ni < 4; ++ni) {
        int oc = w * 64 + ni * 16 + lr;
        bfr[ni] = *(const shortx8*)&Blds[oc * 64 + ((slotbase ^ (oc & 7)) << 3)];
      }
#pragma unroll
      for (int mi = 0; mi < 2; ++mi)
#pragma unroll
        for (int ni = 0; ni < 4; ++ni)
          acc[mi][ni] = __builtin_amdgcn_mfma_f32_16x16x32_bf16(af[mi], bfr[ni], acc[mi][ni], 0, 0, 0);
    }
  }

  // ---- deterministic denom reduction: 8 threads per dst row ----
  dsums[t] = dsum;
  __syncthreads();
  if (t < 32) {
    float s = 0.f;
#pragma unroll
    for (int w2 = 0; w2 < 4; ++w2) {
      s += dsums[w2 * 64 + t * 2];
      s += dsums[w2 * 64 + t * 2 + 1];
    }
    denr[t] = s;                     // raw (clamped at use / in reducer)
  }
  __syncthreads();

  // ---- write ----
#pragma unroll
  for (int mi = 0; mi < 2; ++mi) {
#pragma unroll
    for (int reg = 0; reg < 4; ++reg) {
      int rl = mi * 16 + lg * 4 + reg;
      int row = dst0 + rl;
      float dinv = 0.f;
      if (KSPLIT == 1) dinv = 1.f / fmaxf(denr[rl], 1e-16f);
#pragma unroll
      for (int ni = 0; ni < 4; ++ni) {
        int col = w * 64 + ni * 16 + lr;
        float v = acc[mi][ni][reg];
        size_t idx = (((size_t)b << 10) + row) * 256 + col;
        if (KSPLIT == 1) outp[idx] = v * dinv;
        else             pout[(size_t)kc * 2097152 + idx] = v;
      }
    }
  }
  if (KSPLIT == 2 && t < 32) dpart[kc * 8192 + (b << 10) + dst0 + t] = denr[t];
}

// ---------------- kernel 3: split-K reduce + normalize ----------------
__global__ __launch_bounds__(256) void k3_reduce(const float* __restrict__ pout,
                                                 const float* __restrict__ dpart,
                                                 float* __restrict__ outp) {
  int bid = blockIdx.x;              // b*1024 + dst, 8192 blocks
  size_t base = (size_t)bid * 256 + threadIdx.x;
  float v = pout[base] + pout[2097152 + base];
  float d = dpart[bid] + dpart[8192 + bid];
  outp[base] = v / fmaxf(d, 1e-16f);
}

// ---------------- launch ----------------
extern "C" void kernel_launch(void* const* d_in, const int* in_sizes, int n_in,
                              void* d_out, int out_size, void* d_ws, size_t ws_size,
                              hipStream_t stream) {
  const float* x   = (const float*)d_in[0];
  const float* adj = (const float*)d_in[1];
  const float* w   = (const float*)d_in[2];
  float* out = (float*)d_out;

  char* ws = (char*)d_ws;
  unsigned short* ft  = (unsigned short*)(ws);              // 32 MB  f_t[b][o][k]
  unsigned short* xbf = (unsigned short*)(ws + 33554432);   //  4 MB
  unsigned short* wt  = (unsigned short*)(ws + 37748736);   //  1 MB
  float* pout  = (float*)(ws + 38797312);                   // 16 MB  (split-K partials)
  float* dpart = (float*)(ws + 55574528);                   // 64 KB

  prep_x<<<1024, 256, 0, stream>>>(x, xbf);
  prep_w<<<2048, 256, 0, stream>>>(w, wt);
  k1_gemm<<<1024, 256, 0, stream>>>(xbf, wt, ft);

  if (ws_size >= 55640064ull) {
    k2_gemm<2><<<512, 256, 0, stream>>>(adj, ft, out, pout, dpart);
    k3_reduce<<<8192, 256, 0, stream>>>(pout, dpart, out);
  } else {
    k2_gemm<1><<<256, 256, 0, stream>>>(adj, ft, out, pout, dpart);
  }
}